// Round 7
// baseline (4717.168 us; speedup 1.0000x reference)
//
#include <hip/hip_runtime.h>
#include <hip/hip_bf16.h>
#include <stdint.h>

// Problem constants
#define B_ 8
#define H_ 512
#define F_ 256
#define P_ 12
#define M_ 4096          // B*H
#define K1_ 16384        // N*F = 64*256
#define J_ 1024          // 4*F

typedef __attribute__((ext_vector_type(8))) short short8;
typedef __attribute__((ext_vector_type(4))) float floatx4;

union FragU { uint4 u; short8 s; };

// Workspace layout (bytes)
#define OFF_W1H   ((size_t)0)          //  8,388,608  W1 swizzled bf16 hi
#define OFF_W1L   ((size_t)8388608)    //  8,388,608  W1 swizzled bf16 lo
#define OFF_WHSW  ((size_t)16777216)   //    524,288  Wh swizzled bf16
#define OFF_ENC   ((size_t)17301504)   //  4,194,304  encoder states fp32 [8][512][256]
#define OFF_C     ((size_t)21495808)   //      8,192  c state [8][256]
#define OFF_XSUM  ((size_t)21504000)   //  4,194,304  xs transposed [256][4096]
#define OFF_XPRE  ((size_t)25698304)   // 16,777,216  Xpre [4096][1024]
#define OFF_P1    ((size_t)42475520)   // 33,554,432  split-K partials [8][256][4096]
// Decoder state aliases INTO the P1 region (P1 dead after k_reduce):
#define OFF_ENCT  (OFF_P1)                    // 4,194,304  encT [8][256 k][512 t]
#define OFF_HST   (OFF_P1 + (size_t)4194304)  //     8,192  h state [8][256]
#define OFF_CTXG  (OFF_HST + (size_t)8192)    //     8,192  ctx [8][256]
#define OFF_ZG    (OFF_CTXG + (size_t)8192)   //    32,768  z [8][1024]

__device__ __forceinline__ unsigned short f2bf(float f) {
  uint32_t u = __float_as_uint(f);
  u += 0x7fffu + ((u >> 16) & 1u);
  return (unsigned short)(u >> 16);
}
__device__ __forceinline__ float bf2f(unsigned short h) {
  return __uint_as_float(((uint32_t)h) << 16);
}
__device__ __forceinline__ float sigm(float x) { return 1.f / (1.f + __expf(-x)); }
__device__ __forceinline__ float tanh_(float x) {
  float ax = fabsf(x);
  float e  = __expf(-2.f * ax);
  float t  = (1.f - e) / (1.f + e);
  return x < 0.f ? -t : t;
}

// ---------------------------------------------------------------------------
// Prep: W1 -> bf16 hi/lo in MFMA A-fragment swizzled layout.
__global__ void k_prep_w1(const float* __restrict__ W1,
                          uint4* __restrict__ hi, uint4* __restrict__ lo) {
  int idx  = blockIdx.x * 1024 + threadIdx.x;     // 0..524287
  int lane = idx & 63;
  int kt   = (idx >> 6) & 511;
  int nt   = idx >> 15;                            // 0..15
  int n    = nt * 16 + (lane & 15);
  int kb   = kt * 32 + ((lane >> 4) << 3);
  unsigned short h8[8], l8[8];
#pragma unroll
  for (int j = 0; j < 8; ++j) {
    float v = W1[(size_t)(kb + j) * 256 + n];
    unsigned short hh = f2bf(v);
    h8[j] = hh;
    l8[j] = f2bf(v - bf2f(hh));
  }
  uint4 uh, ul;
  uh.x = (uint32_t)h8[0] | ((uint32_t)h8[1] << 16);
  uh.y = (uint32_t)h8[2] | ((uint32_t)h8[3] << 16);
  uh.z = (uint32_t)h8[4] | ((uint32_t)h8[5] << 16);
  uh.w = (uint32_t)h8[6] | ((uint32_t)h8[7] << 16);
  ul.x = (uint32_t)l8[0] | ((uint32_t)l8[1] << 16);
  ul.y = (uint32_t)l8[2] | ((uint32_t)l8[3] << 16);
  ul.z = (uint32_t)l8[4] | ((uint32_t)l8[5] << 16);
  ul.w = (uint32_t)l8[6] | ((uint32_t)l8[7] << 16);
  hi[idx] = uh;
  lo[idx] = ul;
}

// Wh -> bf16 swizzled A-fragments. Fragment (zt, kt): m = z col, k = h index.
__global__ void k_prep_wh(const float* __restrict__ Wh, uint4* __restrict__ sw) {
  int idx  = blockIdx.x * 1024 + threadIdx.x;     // 0..32767
  int lane = idx & 63;
  int kt   = (idx >> 6) & 7;
  int zt   = idx >> 9;                             // 0..63
  int col  = zt * 16 + (lane & 15);
  int kb   = kt * 32 + ((lane >> 4) << 3);
  unsigned short h8[8];
#pragma unroll
  for (int j = 0; j < 8; ++j) h8[j] = f2bf(Wh[(size_t)(kb + j) * 1024 + col]);
  uint4 u;
  u.x = (uint32_t)h8[0] | ((uint32_t)h8[1] << 16);
  u.y = (uint32_t)h8[2] | ((uint32_t)h8[3] << 16);
  u.z = (uint32_t)h8[4] | ((uint32_t)h8[5] << 16);
  u.w = (uint32_t)h8[6] | ((uint32_t)h8[7] << 16);
  sw[idx] = u;
}

// ---------------------------------------------------------------------------
// GEMM1 split-K (unchanged)
__global__ __launch_bounds__(1024)
void k_gemm1(const float* __restrict__ x, const uint4* __restrict__ w1h,
             const uint4* __restrict__ w1l, float* __restrict__ P1) {
  __shared__ __align__(16) unsigned short xh[128 * 40];
  __shared__ __align__(16) unsigned short xl[128 * 40];
  int bm = blockIdx.x >> 3, kc = blockIdx.x & 7;
  int m0 = bm * 128, kcbase = kc * 2048;
  int tid = threadIdx.x, wave = tid >> 6, lane = tid & 63;
  int quad = lane >> 4, l15 = lane & 15;
  int srow = tid >> 3, skch = tid & 7;
  floatx4 acc[8];
#pragma unroll
  for (int mt = 0; mt < 8; ++mt) acc[mt] = (floatx4)(0.f);

  const float* xrow = x + (size_t)(m0 + srow) * K1_ + kcbase + skch * 4;
  float4 xv = *(const float4*)(xrow);
  for (int it = 0; it < 64; ++it) {
    unsigned short h0 = f2bf(xv.x), h1 = f2bf(xv.y), h2 = f2bf(xv.z), h3 = f2bf(xv.w);
    unsigned short g0 = f2bf(xv.x - bf2f(h0)), g1 = f2bf(xv.y - bf2f(h1));
    unsigned short g2 = f2bf(xv.z - bf2f(h2)), g3 = f2bf(xv.w - bf2f(h3));
    uint2 ph, pl;
    ph.x = (uint32_t)h0 | ((uint32_t)h1 << 16); ph.y = (uint32_t)h2 | ((uint32_t)h3 << 16);
    pl.x = (uint32_t)g0 | ((uint32_t)g1 << 16); pl.y = (uint32_t)g2 | ((uint32_t)g3 << 16);
    *(uint2*)&xh[srow * 40 + skch * 4] = ph;
    *(uint2*)&xl[srow * 40 + skch * 4] = pl;
    __syncthreads();

    float4 xn = xv;
    if (it < 63) xn = *(const float4*)(xrow + (it + 1) * 32);

    size_t aoff = (size_t)(wave * 512 + kc * 64 + it) * 64 + lane;
    FragU ah; ah.u = w1h[aoff];
    FragU al; al.u = w1l[aoff];
#pragma unroll
    for (int mt = 0; mt < 8; ++mt) {
      FragU bh, bl;
      bh.u = *(const uint4*)&xh[(mt * 16 + l15) * 40 + quad * 8];
      bl.u = *(const uint4*)&xl[(mt * 16 + l15) * 40 + quad * 8];
      acc[mt] = __builtin_amdgcn_mfma_f32_16x16x32_bf16(ah.s, bh.s, acc[mt], 0, 0, 0);
      acc[mt] = __builtin_amdgcn_mfma_f32_16x16x32_bf16(ah.s, bl.s, acc[mt], 0, 0, 0);
      acc[mt] = __builtin_amdgcn_mfma_f32_16x16x32_bf16(al.s, bh.s, acc[mt], 0, 0, 0);
    }
    __syncthreads();
    xv = xn;
  }
  int nbase = wave * 16 + quad * 4;
#pragma unroll
  for (int mt = 0; mt < 8; ++mt) {
    int m = m0 + mt * 16 + l15;
#pragma unroll
    for (int r = 0; r < 4; ++r)
      P1[(size_t)(kc * 256 + nbase + r) * M_ + m] = acc[mt][r];
  }
}

// Sum split-K partials + b1 -> xsum[k][m]
__global__ void k_reduce(const float* __restrict__ P1, const float* __restrict__ b1,
                         float* __restrict__ xsum) {
  int idx = blockIdx.x * 1024 + threadIdx.x;       // 1,048,576
  int k = idx >> 12, m = idx & 4095;
  float s = b1[k];
#pragma unroll
  for (int kc = 0; kc < 8; ++kc) s += P1[(size_t)(kc * 256 + k) * M_ + m];
  xsum[(size_t)k * M_ + m] = s;
}

// GEMM2 (fp32 VALU)
__global__ __launch_bounds__(256)
void k_gemm2(const float* __restrict__ xsum, const float* __restrict__ Wx,
             const float* __restrict__ bz, float* __restrict__ Xpre) {
  int m0 = blockIdx.x * 16;
  int j = threadIdx.x;
  float acc0[16], acc1[16], acc2[16], acc3[16];
  float bb0 = bz[j], bb1 = bz[256 + j], bb2 = bz[512 + j], bb3 = bz[768 + j];
#pragma unroll
  for (int mm = 0; mm < 16; ++mm) { acc0[mm] = bb0; acc1[mm] = bb1; acc2[mm] = bb2; acc3[mm] = bb3; }
#pragma unroll 4
  for (int k = 0; k < 256; ++k) {
    float w0 = Wx[(size_t)k * 1024 + j];
    float w1 = Wx[(size_t)k * 1024 + 256 + j];
    float w2 = Wx[(size_t)k * 1024 + 512 + j];
    float w3 = Wx[(size_t)k * 1024 + 768 + j];
#pragma unroll
    for (int mm = 0; mm < 16; ++mm) {
      float xv = xsum[(size_t)k * M_ + m0 + mm];
      acc0[mm] += xv * w0; acc1[mm] += xv * w1; acc2[mm] += xv * w2; acc3[mm] += xv * w3;
    }
  }
#pragma unroll
  for (int mm = 0; mm < 16; ++mm) {
    float* o = Xpre + (size_t)(m0 + mm) * 1024;
    o[j] = acc0[mm]; o[256 + j] = acc1[mm]; o[512 + j] = acc2[mm]; o[768 + j] = acc3[mm];
  }
}

// ---------------------------------------------------------------------------
// Encoder v8: gates computed IN-REGISTER from the MFMA accumulators.
//   D layout (16x16x32): col=lane&15, row=(lane>>4)*4+reg. col0=W*h_hi,
//   col1=W*h_lo -> z = a + shfl_xor(a,1). By the tile->wave mapping
//   (zt = 16*(i>>1) + 2w + (i&1)), the 4 gates of unit j=32w+16hf+4q+r sit
//   at the same (lane,reg) across accs a[hf],a[2+hf],a[4+hf],a[6+hf].
//   Eliminates the zsh LDS round-trip + gate-thread remap entirely.
//   Single-pass kt loop over 8 independent accs (halves hb reads, full MFMA
//   interleave). Xpre staged via dbuf LDS (4KB), prefetched 1 step ahead.
//   46 weight frags/wave in regs (184), 18/wave in LDS (144 KB). One barrier.
__global__ __attribute__((amdgpu_flat_work_group_size(512, 512)))
__attribute__((amdgpu_waves_per_eu(2, 2)))
void k_encoder(const uint4* __restrict__ whsw, const float* __restrict__ Xpre,
               float* __restrict__ enc, float* __restrict__ encT,
               float* __restrict__ cws) {
  __shared__ uint4 wl[9216];                          // 144 KB LDS weight frags
  __shared__ __align__(16) unsigned short hb[2][512]; // dbuf h hi/lo
  __shared__ __align__(16) float xst[2][1024];        // dbuf Xpre row stage
  int b = blockIdx.x, tid = threadIdx.x;
  int wave = tid >> 6, lane = tid & 63;
  int quad = lane >> 4, l15 = lane & 15;

  // stage wl: per wave 18 frags: fi 0..7 = tile i6 kt; 8..15 = i7 kt; 16..17 = i5 kt6,7
  for (int r = 0; r < 18; ++r) {
    int u = r * 512 + tid;                 // 0..9215
    int ln = u & 63, fslot = u >> 6;       // 0..143
    int w = fslot / 18, fi = fslot - w * 18;
    int i = (fi < 8) ? 6 : ((fi < 16) ? 7 : 5);
    int kt = (fi < 8) ? fi : ((fi < 16) ? fi - 8 : fi - 10);
    int zt = 16 * (i >> 1) + 2 * w + (i & 1);
    wl[u] = whsw[(size_t)((zt * 8 + kt) * 64 + ln)];
  }

  // Register-resident weights: tiles i0..4 all kt (40) + i5 kt0..5 (6)
  uint4 wfr[46];
#pragma unroll
  for (int i = 0; i < 5; ++i) {
    int zt = 16 * (i >> 1) + 2 * wave + (i & 1);
#pragma unroll
    for (int kt = 0; kt < 8; ++kt)
      wfr[i * 8 + kt] = whsw[(size_t)((zt * 8 + kt) * 64 + lane)];
  }
  {
    int zt = 33 + 2 * wave;                // i = 5
#pragma unroll
    for (int kt = 0; kt < 6; ++kt)
      wfr[40 + kt] = whsw[(size_t)((zt * 8 + kt) * 64 + lane)];
  }

  hb[0][tid] = 0; hb[1][tid] = 0;
  float cr[8];
#pragma unroll
  for (int u = 0; u < 8; ++u) cr[u] = 0.f;
  const float* xpb = Xpre + (size_t)b * 512 * 1024;
  // stage Xpre row 0
  { float2 v = *(const float2*)(xpb + 2 * tid); *(float2*)&xst[0][2 * tid] = v; }
  int hoff = ((l15 == 1) ? 256 : 0) + quad * 8;
  const uint4* wlw = wl + (size_t)(wave * 18) * 64 + lane;
  int jb = 32 * wave + 4 * quad;                      // hf=0 unit base
  __syncthreads();

  int cur = 0;
  for (int t = 0; t < 512; ++t) {
    const unsigned short* hbc = hb[cur];
    // prefetch next Xpre row (consumed at next step's gates via LDS)
    float2 xnext;
    if (t < 511) xnext = *(const float2*)(xpb + (size_t)(t + 1) * 1024 + 2 * tid);

    floatx4 a0 = (floatx4)(0.f), a1 = (floatx4)(0.f);
    floatx4 a2 = (floatx4)(0.f), a3 = (floatx4)(0.f);
    floatx4 a4 = (floatx4)(0.f), a5 = (floatx4)(0.f);
    floatx4 a6 = (floatx4)(0.f), a7 = (floatx4)(0.f);
#pragma unroll
    for (int kt = 0; kt < 8; ++kt) {
      FragU bf; bf.u = *(const uint4*)&hbc[hoff + kt * 32];
      FragU w0_, w1_, w2_, w3_, w4_, w5_, w6_, w7_;
      w0_.u = wfr[0 + kt];  w1_.u = wfr[8 + kt];
      w2_.u = wfr[16 + kt]; w3_.u = wfr[24 + kt];
      w4_.u = wfr[32 + kt];
      w5_.u = (kt < 6) ? wfr[40 + kt] : wlw[(size_t)(16 + (kt - 6)) * 64];
      w6_.u = wlw[(size_t)kt * 64];
      w7_.u = wlw[(size_t)(8 + kt) * 64];
      a0 = __builtin_amdgcn_mfma_f32_16x16x32_bf16(w0_.s, bf.s, a0, 0, 0, 0);
      a1 = __builtin_amdgcn_mfma_f32_16x16x32_bf16(w1_.s, bf.s, a1, 0, 0, 0);
      a2 = __builtin_amdgcn_mfma_f32_16x16x32_bf16(w2_.s, bf.s, a2, 0, 0, 0);
      a3 = __builtin_amdgcn_mfma_f32_16x16x32_bf16(w3_.s, bf.s, a3, 0, 0, 0);
      a4 = __builtin_amdgcn_mfma_f32_16x16x32_bf16(w4_.s, bf.s, a4, 0, 0, 0);
      a5 = __builtin_amdgcn_mfma_f32_16x16x32_bf16(w5_.s, bf.s, a5, 0, 0, 0);
      a6 = __builtin_amdgcn_mfma_f32_16x16x32_bf16(w6_.s, bf.s, a6, 0, 0, 0);
      a7 = __builtin_amdgcn_mfma_f32_16x16x32_bf16(w7_.s, bf.s, a7, 0, 0, 0);
    }

    // combine hi(col0)+lo(col1) products: z = a + shfl_xor(a,1)
#define COMB(Z, A) floatx4 Z; { \
  _Pragma("unroll") for (int r_ = 0; r_ < 4; ++r_) \
    Z[r_] = A[r_] + __shfl_xor(A[r_], 1, 64); }
    COMB(za0, a0) COMB(za1, a1) COMB(za2, a2) COMB(za3, a3)
    COMB(za4, a4) COMB(za5, a5) COMB(za6, a6) COMB(za7, a7)
#undef COMB

    // gates (valid in lanes l15 in {0,1}; others compute garbage, never store)
    const float* xc = xst[cur];
    floatx4 xi0 = *(const floatx4*)&xc[jb];
    floatx4 xf0 = *(const floatx4*)&xc[256 + jb];
    floatx4 xg0 = *(const floatx4*)&xc[512 + jb];
    floatx4 xo0 = *(const floatx4*)&xc[768 + jb];
    floatx4 xi1 = *(const floatx4*)&xc[16 + jb];
    floatx4 xf1 = *(const floatx4*)&xc[272 + jb];
    floatx4 xg1 = *(const floatx4*)&xc[528 + jb];
    floatx4 xo1 = *(const floatx4*)&xc[784 + jb];
    float hn[8];
#define GATEBLK(HF, ZI, ZF, ZG, ZO, XI, XF, XG, XO) { \
  _Pragma("unroll") for (int r_ = 0; r_ < 4; ++r_) { \
    float zi = ZI[r_] + XI[r_]; \
    float zf = ZF[r_] + XF[r_]; \
    float zg = ZG[r_] + XG[r_]; \
    float zo = ZO[r_] + XO[r_]; \
    float ig = sigm(zi), fg = sigm(zf); \
    float gg = tanh_(zg), og = sigm(zo); \
    float cn = fg * cr[(HF) * 4 + r_] + ig * gg; \
    cr[(HF) * 4 + r_] = cn; \
    hn[(HF) * 4 + r_] = og * tanh_(cn); } }
    GATEBLK(0, za0, za2, za4, za6, xi0, xf0, xg0, xo0)
    GATEBLK(1, za1, za3, za5, za7, xi1, xf1, xg1, xo1)
#undef GATEBLK

    int nxt = cur ^ 1;
    unsigned short* hbn = hb[nxt];
    if (l15 == 0) {
      unsigned short hi8[8], lo8[8];
#pragma unroll
      for (int u = 0; u < 8; ++u) {
        unsigned short hh = f2bf(hn[u]);
        hi8[u] = hh;
        lo8[u] = f2bf(hn[u] - bf2f(hh));
      }
      uint2 w0, w1;
      w0.x = (uint32_t)hi8[0] | ((uint32_t)hi8[1] << 16);
      w0.y = (uint32_t)hi8[2] | ((uint32_t)hi8[3] << 16);
      w1.x = (uint32_t)hi8[4] | ((uint32_t)hi8[5] << 16);
      w1.y = (uint32_t)hi8[6] | ((uint32_t)hi8[7] << 16);
      *(uint2*)&hbn[jb] = w0;
      *(uint2*)&hbn[16 + jb] = w1;
      w0.x = (uint32_t)lo8[0] | ((uint32_t)lo8[1] << 16);
      w0.y = (uint32_t)lo8[2] | ((uint32_t)lo8[3] << 16);
      w1.x = (uint32_t)lo8[4] | ((uint32_t)lo8[5] << 16);
      w1.y = (uint32_t)lo8[6] | ((uint32_t)lo8[7] << 16);
      *(uint2*)&hbn[256 + jb] = w0;
      *(uint2*)&hbn[272 + jb] = w1;
      // enc (coalesced-ish float4) + encT (strided scalars)
      float* encrow = enc + ((size_t)b * 512 + t) * 256;
      floatx4 e0, e1;
      e0[0] = hn[0]; e0[1] = hn[1]; e0[2] = hn[2]; e0[3] = hn[3];
      e1[0] = hn[4]; e1[1] = hn[5]; e1[2] = hn[6]; e1[3] = hn[7];
      *(floatx4*)&encrow[jb] = e0;
      *(floatx4*)&encrow[16 + jb] = e1;
      float* eTb = encT + (size_t)b * 256 * 512 + t;
#pragma unroll
      for (int r = 0; r < 4; ++r) {
        eTb[(size_t)(jb + r) * 512] = hn[r];
        eTb[(size_t)(jb + 16 + r) * 512] = hn[4 + r];
      }
    }
    // stage next Xpre row into the other buffer
    if (t < 511) *(float2*)&xst[nxt][2 * tid] = xnext;
    __syncthreads();
    cur = nxt;
  }
  if (l15 == 0) {
#pragma unroll
    for (int r = 0; r < 4; ++r) {
      cws[b * 256 + jb + r] = cr[r];
      cws[b * 256 + jb + 16 + r] = cr[4 + r];
    }
  }
}

// ---------------------------------------------------------------------------
// Decoder step kernel A (round-3 proven): cell + out + q + scores + softmax
// + ctx. One block per batch, 1024 threads.
__global__ __launch_bounds__(1024)
void k_dec_att(const float* __restrict__ enc, const float* __restrict__ encT,
               float* __restrict__ hst, float* __restrict__ cst,
               const float* __restrict__ zg, float* __restrict__ ctxg,
               const float* __restrict__ Wa, const float* __restrict__ ba,
               const float* __restrict__ W2, const float* __restrict__ b2,
               float* __restrict__ out, int p) {
  __shared__ float hsh[256], qsh[256], sc[512], smx[2];
  __shared__ float zb[1024];
  int b = blockIdx.x, tid = threadIdx.x;
  const float* encb = enc + (size_t)b * 512 * 256;

  if (p > 0) {
    if (tid < 256) {
      float zi = zg[b * 1024 + tid];
      float zf = zg[b * 1024 + 256 + tid];
      float zgg = zg[b * 1024 + 512 + tid];
      float zo = zg[b * 1024 + 768 + tid];
      float ig = sigm(zi), fg = sigm(zf), gg = tanh_(zgg), og = sigm(zo);
      float cn = fg * cst[b * 256 + tid] + ig * gg;
      cst[b * 256 + tid] = cn;
      float hn = og * tanh_(cn);
      hsh[tid] = hn;
      hst[b * 256 + tid] = hn;
    }
    __syncthreads();
    if (tid < 512) {
      int col = tid & 63, kc = tid >> 6;     // kc 0..7
      float s = 0.f;
#pragma unroll
      for (int i = 0; i < 32; ++i) {
        int k = kc * 32 + i;
        s += hsh[k] * W2[(size_t)k * 64 + col];
      }
      zb[tid] = s;
    }
    __syncthreads();
    if (tid < 64) {
      float s = b2[tid];
#pragma unroll
      for (int kc = 0; kc < 8; ++kc) s += zb[kc * 64 + tid];
      out[((size_t)b * 12 + (p - 1)) * 64 + tid] = s;
    }
  } else {
    if (tid < 256) {
      float hv = encb[(size_t)511 * 256 + tid];
      hsh[tid] = hv;
      hst[b * 256 + tid] = hv;
    }
  }
  if (p == 12) return;
  __syncthreads();

  // q = h @ Wa + ba   (k split 4 ways)
  {
    int j = tid & 255, kc = tid >> 8;
    float s = 0.f;
#pragma unroll 8
    for (int i = 0; i < 64; ++i) {
      int k = kc * 64 + i;
      s += hsh[k] * Wa[(size_t)k * 256 + j];
    }
    zb[tid] = s;
  }
  __syncthreads();
  if (tid < 256) qsh[tid] = ba[tid] + zb[tid] + zb[256 + tid] + zb[512 + tid] + zb[768 + tid];
  __syncthreads();

  // scores via encT (coalesced over hh, k split 2 ways)
  {
    int hh = tid & 511, kc = tid >> 9;
    const float* eT = encT + (size_t)b * 256 * 512;
    float s = 0.f;
#pragma unroll 8
    for (int i = 0; i < 128; ++i) {
      int k = kc * 128 + i;
      s += qsh[k] * eT[(size_t)k * 512 + hh];
    }
    zb[tid] = s;
  }
  __syncthreads();
  if (tid < 512) sc[tid] = zb[tid] + zb[512 + tid];
  __syncthreads();

  if (tid < 64) {
    float m = -3.4e38f;
#pragma unroll
    for (int r = 0; r < 8; ++r) m = fmaxf(m, sc[tid * 8 + r]);
#pragma unroll
    for (int off = 32; off >= 1; off >>= 1) m = fmaxf(m, __shfl_xor(m, off, 64));
    if (tid == 0) smx[0] = m;
  }
  __syncthreads();
  if (tid < 512) sc[tid] = __expf(sc[tid] - smx[0]);
  __syncthreads();
  if (tid < 64) {
    float s = 0.f;
#pragma unroll
    for (int r = 0; r < 8; ++r) s += sc[tid * 8 + r];
#pragma unroll
    for (int off = 32; off >= 1; off >>= 1) s += __shfl_xor(s, off, 64);
    if (tid == 0) smx[1] = 1.f / s;
  }
  __syncthreads();

  // ctx = softmax . enc   (hh split 4 ways)
  {
    int j = tid & 255, hs = tid >> 8;
    float s = 0.f;
#pragma unroll 8
    for (int r = 0; r < 128; ++r) {
      int hh = hs * 128 + r;
      s += sc[hh] * encb[(size_t)hh * 256 + j];
    }
    zb[tid] = s;
  }
  __syncthreads();
  if (tid < 256)
    ctxg[b * 256 + tid] = (zb[tid] + zb[256 + tid] + zb[512 + tid] + zb[768 + tid]) * smx[1];
}

// ---------------------------------------------------------------------------
// Decoder step kernel B (round-3 proven): z = ctx@Wx + h@Wh + bz, 64 blocks.
__global__ __launch_bounds__(512)
void k_dec_z(const float* __restrict__ ctxg, const float* __restrict__ hst,
             const float* __restrict__ Wx, const float* __restrict__ Wh,
             const float* __restrict__ bz, float* __restrict__ zg) {
  __shared__ float ldsx[256], ldsh[256], zsh[512];
  int chunk = blockIdx.x & 7, b = blockIdx.x >> 3;
  int tid = threadIdx.x;
  int j = tid & 127, ks = (tid >> 7) & 1, sel = tid >> 8;
  int col = chunk * 128 + j;

  if (tid < 256) ldsx[tid] = ctxg[b * 256 + tid];
  else ldsh[tid - 256] = hst[b * 256 + (tid - 256)];
  __syncthreads();

  const float* W = sel ? Wh : Wx;
  const float* v = sel ? ldsh : ldsx;
  float s = 0.f;
#pragma unroll 8
  for (int i = 0; i < 128; ++i) {
    int k = ks * 128 + i;
    s += v[k] * W[(size_t)k * 1024 + col];
  }
  zsh[tid] = s;
  __syncthreads();
  if (tid < 128)
    zg[b * 1024 + col] = bz[col] + zsh[j] + zsh[128 + j] + zsh[256 + j] + zsh[384 + j];
}

// ---------------------------------------------------------------------------
extern "C" void kernel_launch(void* const* d_in, const int* in_sizes, int n_in,
                              void* d_out, int out_size, void* d_ws, size_t ws_size,
                              hipStream_t stream) {
  const float* x  = (const float*)d_in[0];
  const float* W1 = (const float*)d_in[1];
  const float* b1 = (const float*)d_in[2];
  const float* Wx = (const float*)d_in[3];
  const float* Wh = (const float*)d_in[4];
  const float* bz = (const float*)d_in[5];
  const float* Wa = (const float*)d_in[6];
  const float* ba = (const float*)d_in[7];
  const float* W2 = (const float*)d_in[8];
  const float* b2 = (const float*)d_in[9];

  char* ws = (char*)d_ws;
  uint4* w1h  = (uint4*)(ws + OFF_W1H);
  uint4* w1l  = (uint4*)(ws + OFF_W1L);
  uint4* whsw = (uint4*)(ws + OFF_WHSW);
  float* enc  = (float*)(ws + OFF_ENC);
  float* cws  = (float*)(ws + OFF_C);
  float* xsum = (float*)(ws + OFF_XSUM);
  float* xpre = (float*)(ws + OFF_XPRE);
  float* p1   = (float*)(ws + OFF_P1);
  float* encT = (float*)(ws + OFF_ENCT);
  float* hst  = (float*)(ws + OFF_HST);
  float* ctxg = (float*)(ws + OFF_CTXG);
  float* zg   = (float*)(ws + OFF_ZG);

  k_prep_w1<<<dim3(512), dim3(1024), 0, stream>>>(W1, w1h, w1l);
  k_prep_wh<<<dim3(32), dim3(1024), 0, stream>>>(Wh, whsw);
  k_gemm1<<<dim3(256), dim3(1024), 0, stream>>>(x, w1h, w1l, p1);
  k_reduce<<<dim3(1024), dim3(1024), 0, stream>>>(p1, b1, xsum);
  k_gemm2<<<dim3(256), dim3(256), 0, stream>>>(xsum, Wx, bz, xpre);
  k_encoder<<<dim3(8), dim3(512), 0, stream>>>(whsw, xpre, enc, encT, cws);
  for (int p = 0; p <= 12; ++p) {
    k_dec_att<<<dim3(8), dim3(1024), 0, stream>>>(enc, encT, hst, cws, zg, ctxg,
                                                  Wa, ba, W2, b2, (float*)d_out, p);
    if (p < 12)
      k_dec_z<<<dim3(64), dim3(512), 0, stream>>>(ctxg, hst, Wx, Wh, bz, zg);
  }
}

// Round 8
// 1798.860 us; speedup vs baseline: 2.6223x; 2.6223x over previous
//
#include <hip/hip_runtime.h>
#include <hip/hip_bf16.h>
#include <stdint.h>

// Problem constants
#define B_ 8
#define H_ 512
#define F_ 256
#define P_ 12
#define M_ 4096          // B*H
#define K1_ 16384        // N*F = 64*256
#define J_ 1024          // 4*F

typedef __attribute__((ext_vector_type(8))) short short8;
typedef __attribute__((ext_vector_type(4))) float floatx4;

union FragU { uint4 u; short8 s; };

// Workspace layout (bytes)
#define OFF_W1H   ((size_t)0)          //  8,388,608  W1 swizzled bf16 hi
#define OFF_W1L   ((size_t)8388608)    //  8,388,608  W1 swizzled bf16 lo
#define OFF_WHSW  ((size_t)16777216)   //    524,288  Wh swizzled bf16
#define OFF_ENC   ((size_t)17301504)   //  4,194,304  encoder states fp32 [8][512][256]
#define OFF_C     ((size_t)21495808)   //      8,192  c state [8][256]
#define OFF_XSUM  ((size_t)21504000)   //  4,194,304  xs transposed [256][4096]
#define OFF_XPRE  ((size_t)25698304)   // 16,777,216  Xpre [4096][1024]
#define OFF_P1    ((size_t)42475520)   // 33,554,432  split-K partials [8][256][4096]
// Decoder state aliases INTO the P1 region (P1 dead after k_reduce):
#define OFF_ENCT  (OFF_P1)                    // 4,194,304  encT [8][256 k][512 t]
#define OFF_HST   (OFF_P1 + (size_t)4194304)  //     8,192  h state [8][256]
#define OFF_CTXG  (OFF_HST + (size_t)8192)    //     8,192  ctx [8][256]
#define OFF_ZG    (OFF_CTXG + (size_t)8192)   //    32,768  z [8][1024]

__device__ __forceinline__ unsigned short f2bf(float f) {
  uint32_t u = __float_as_uint(f);
  u += 0x7fffu + ((u >> 16) & 1u);
  return (unsigned short)(u >> 16);
}
__device__ __forceinline__ float bf2f(unsigned short h) {
  return __uint_as_float(((uint32_t)h) << 16);
}
__device__ __forceinline__ float sigm(float x) { return 1.f / (1.f + __expf(-x)); }
__device__ __forceinline__ float tanh_(float x) {
  float ax = fabsf(x);
  float e  = __expf(-2.f * ax);
  float t  = (1.f - e) / (1.f + e);
  return x < 0.f ? -t : t;
}

// ---------------------------------------------------------------------------
// Prep: W1 -> bf16 hi/lo in MFMA A-fragment swizzled layout.
__global__ void k_prep_w1(const float* __restrict__ W1,
                          uint4* __restrict__ hi, uint4* __restrict__ lo) {
  int idx  = blockIdx.x * 1024 + threadIdx.x;     // 0..524287
  int lane = idx & 63;
  int kt   = (idx >> 6) & 511;
  int nt   = idx >> 15;                            // 0..15
  int n    = nt * 16 + (lane & 15);
  int kb   = kt * 32 + ((lane >> 4) << 3);
  unsigned short h8[8], l8[8];
#pragma unroll
  for (int j = 0; j < 8; ++j) {
    float v = W1[(size_t)(kb + j) * 256 + n];
    unsigned short hh = f2bf(v);
    h8[j] = hh;
    l8[j] = f2bf(v - bf2f(hh));
  }
  uint4 uh, ul;
  uh.x = (uint32_t)h8[0] | ((uint32_t)h8[1] << 16);
  uh.y = (uint32_t)h8[2] | ((uint32_t)h8[3] << 16);
  uh.z = (uint32_t)h8[4] | ((uint32_t)h8[5] << 16);
  uh.w = (uint32_t)h8[6] | ((uint32_t)h8[7] << 16);
  ul.x = (uint32_t)l8[0] | ((uint32_t)l8[1] << 16);
  ul.y = (uint32_t)l8[2] | ((uint32_t)l8[3] << 16);
  ul.z = (uint32_t)l8[4] | ((uint32_t)l8[5] << 16);
  ul.w = (uint32_t)l8[6] | ((uint32_t)l8[7] << 16);
  hi[idx] = uh;
  lo[idx] = ul;
}

// Wh -> bf16 swizzled A-fragments. Fragment (zt, kt): m = z col, k = h index.
__global__ void k_prep_wh(const float* __restrict__ Wh, uint4* __restrict__ sw) {
  int idx  = blockIdx.x * 1024 + threadIdx.x;     // 0..32767
  int lane = idx & 63;
  int kt   = (idx >> 6) & 7;
  int zt   = idx >> 9;                             // 0..63
  int col  = zt * 16 + (lane & 15);
  int kb   = kt * 32 + ((lane >> 4) << 3);
  unsigned short h8[8];
#pragma unroll
  for (int j = 0; j < 8; ++j) h8[j] = f2bf(Wh[(size_t)(kb + j) * 1024 + col]);
  uint4 u;
  u.x = (uint32_t)h8[0] | ((uint32_t)h8[1] << 16);
  u.y = (uint32_t)h8[2] | ((uint32_t)h8[3] << 16);
  u.z = (uint32_t)h8[4] | ((uint32_t)h8[5] << 16);
  u.w = (uint32_t)h8[6] | ((uint32_t)h8[7] << 16);
  sw[idx] = u;
}

// ---------------------------------------------------------------------------
// GEMM1 split-K (unchanged)
__global__ __launch_bounds__(1024)
void k_gemm1(const float* __restrict__ x, const uint4* __restrict__ w1h,
             const uint4* __restrict__ w1l, float* __restrict__ P1) {
  __shared__ __align__(16) unsigned short xh[128 * 40];
  __shared__ __align__(16) unsigned short xl[128 * 40];
  int bm = blockIdx.x >> 3, kc = blockIdx.x & 7;
  int m0 = bm * 128, kcbase = kc * 2048;
  int tid = threadIdx.x, wave = tid >> 6, lane = tid & 63;
  int quad = lane >> 4, l15 = lane & 15;
  int srow = tid >> 3, skch = tid & 7;
  floatx4 acc[8];
#pragma unroll
  for (int mt = 0; mt < 8; ++mt) acc[mt] = (floatx4)(0.f);

  const float* xrow = x + (size_t)(m0 + srow) * K1_ + kcbase + skch * 4;
  float4 xv = *(const float4*)(xrow);
  for (int it = 0; it < 64; ++it) {
    unsigned short h0 = f2bf(xv.x), h1 = f2bf(xv.y), h2 = f2bf(xv.z), h3 = f2bf(xv.w);
    unsigned short g0 = f2bf(xv.x - bf2f(h0)), g1 = f2bf(xv.y - bf2f(h1));
    unsigned short g2 = f2bf(xv.z - bf2f(h2)), g3 = f2bf(xv.w - bf2f(h3));
    uint2 ph, pl;
    ph.x = (uint32_t)h0 | ((uint32_t)h1 << 16); ph.y = (uint32_t)h2 | ((uint32_t)h3 << 16);
    pl.x = (uint32_t)g0 | ((uint32_t)g1 << 16); pl.y = (uint32_t)g2 | ((uint32_t)g3 << 16);
    *(uint2*)&xh[srow * 40 + skch * 4] = ph;
    *(uint2*)&xl[srow * 40 + skch * 4] = pl;
    __syncthreads();

    float4 xn = xv;
    if (it < 63) xn = *(const float4*)(xrow + (it + 1) * 32);

    size_t aoff = (size_t)(wave * 512 + kc * 64 + it) * 64 + lane;
    FragU ah; ah.u = w1h[aoff];
    FragU al; al.u = w1l[aoff];
#pragma unroll
    for (int mt = 0; mt < 8; ++mt) {
      FragU bh, bl;
      bh.u = *(const uint4*)&xh[(mt * 16 + l15) * 40 + quad * 8];
      bl.u = *(const uint4*)&xl[(mt * 16 + l15) * 40 + quad * 8];
      acc[mt] = __builtin_amdgcn_mfma_f32_16x16x32_bf16(ah.s, bh.s, acc[mt], 0, 0, 0);
      acc[mt] = __builtin_amdgcn_mfma_f32_16x16x32_bf16(ah.s, bl.s, acc[mt], 0, 0, 0);
      acc[mt] = __builtin_amdgcn_mfma_f32_16x16x32_bf16(al.s, bh.s, acc[mt], 0, 0, 0);
    }
    __syncthreads();
    xv = xn;
  }
  int nbase = wave * 16 + quad * 4;
#pragma unroll
  for (int mt = 0; mt < 8; ++mt) {
    int m = m0 + mt * 16 + l15;
#pragma unroll
    for (int r = 0; r < 4; ++r)
      P1[(size_t)(kc * 256 + nbase + r) * M_ + m] = acc[mt][r];
  }
}

// Sum split-K partials + b1 -> xsum[k][m]
__global__ void k_reduce(const float* __restrict__ P1, const float* __restrict__ b1,
                         float* __restrict__ xsum) {
  int idx = blockIdx.x * 1024 + threadIdx.x;       // 1,048,576
  int k = idx >> 12, m = idx & 4095;
  float s = b1[k];
#pragma unroll
  for (int kc = 0; kc < 8; ++kc) s += P1[(size_t)(kc * 256 + k) * M_ + m];
  xsum[(size_t)k * M_ + m] = s;
}

// GEMM2 (fp32 VALU)
__global__ __launch_bounds__(256)
void k_gemm2(const float* __restrict__ xsum, const float* __restrict__ Wx,
             const float* __restrict__ bz, float* __restrict__ Xpre) {
  int m0 = blockIdx.x * 16;
  int j = threadIdx.x;
  float acc0[16], acc1[16], acc2[16], acc3[16];
  float bb0 = bz[j], bb1 = bz[256 + j], bb2 = bz[512 + j], bb3 = bz[768 + j];
#pragma unroll
  for (int mm = 0; mm < 16; ++mm) { acc0[mm] = bb0; acc1[mm] = bb1; acc2[mm] = bb2; acc3[mm] = bb3; }
#pragma unroll 4
  for (int k = 0; k < 256; ++k) {
    float w0 = Wx[(size_t)k * 1024 + j];
    float w1 = Wx[(size_t)k * 1024 + 256 + j];
    float w2 = Wx[(size_t)k * 1024 + 512 + j];
    float w3 = Wx[(size_t)k * 1024 + 768 + j];
#pragma unroll
    for (int mm = 0; mm < 16; ++mm) {
      float xv = xsum[(size_t)k * M_ + m0 + mm];
      acc0[mm] += xv * w0; acc1[mm] += xv * w1; acc2[mm] += xv * w2; acc3[mm] += xv * w3;
    }
  }
#pragma unroll
  for (int mm = 0; mm < 16; ++mm) {
    float* o = Xpre + (size_t)(m0 + mm) * 1024;
    o[j] = acc0[mm]; o[256 + j] = acc1[mm]; o[512 + j] = acc2[mm]; o[768 + j] = acc3[mm];
  }
}

// ---------------------------------------------------------------------------
// Encoder v7 (round-6 verified, 981 us): 512 threads (8 waves), intrinsic
// MFMAs, waves_per_eu(2,2). 46 weight frags/wave nominally register-resident
// (in practice ~128 arch VGPR + ~128 AGPR; some spill remains — accepted),
// 18/wave streamed from LDS (144 KB). Wave-local z tiles, one barrier/step.
__global__ __attribute__((amdgpu_flat_work_group_size(512, 512)))
__attribute__((amdgpu_waves_per_eu(2, 2)))
void k_encoder(const uint4* __restrict__ whsw, const float* __restrict__ Xpre,
               float* __restrict__ enc, float* __restrict__ encT,
               float* __restrict__ cws) {
  __shared__ uint4 wl[9216];                          // 144 KB LDS weight frags
  __shared__ __align__(16) unsigned short hb[2][512]; // dbuf h hi/lo
  __shared__ __align__(16) float zsh[2048];
  int b = blockIdx.x, tid = threadIdx.x;
  int wave = tid >> 6, lane = tid & 63;
  int quad = lane >> 4, l15 = lane & 15;
  int e = tid & 1, j = tid >> 1;

  // stage wl: per wave 18 frags: fi 0..7 = tile i6 kt; 8..15 = i7 kt; 16..17 = i5 kt6,7
  for (int r = 0; r < 18; ++r) {
    int u = r * 512 + tid;                 // 0..9215
    int ln = u & 63, fslot = u >> 6;       // 0..143
    int w = fslot / 18, fi = fslot - w * 18;
    int i = (fi < 8) ? 6 : ((fi < 16) ? 7 : 5);
    int kt = (fi < 8) ? fi : ((fi < 16) ? fi - 8 : fi - 10);
    int zt = 16 * (i >> 1) + 2 * w + (i & 1);
    wl[u] = whsw[(size_t)((zt * 8 + kt) * 64 + ln)];
  }

  // Register-resident weights: tiles i0..4 all kt (40) + i5 kt0..5 (6)
  uint4 wfr[46];
#pragma unroll
  for (int i = 0; i < 5; ++i) {
    int zt = 16 * (i >> 1) + 2 * wave + (i & 1);
#pragma unroll
    for (int kt = 0; kt < 8; ++kt)
      wfr[i * 8 + kt] = whsw[(size_t)((zt * 8 + kt) * 64 + lane)];
  }
  {
    int zt = 33 + 2 * wave;                // i = 5
#pragma unroll
    for (int kt = 0; kt < 6; ++kt)
      wfr[40 + kt] = whsw[(size_t)((zt * 8 + kt) * 64 + lane)];
  }

  hb[0][tid] = 0; hb[1][tid] = 0;
  float c_ = 0.f;
  const float* xpb = Xpre + (size_t)b * 512 * 1024;
  int colA = 256 * e + j;
  int colB = 512 + colA;
  int hoff  = ((l15 == 1) ? 256 : 0) + quad * 8;
  int zwoff = ((l15 == 1) ? 1024 : 0) + quad * 4;
  const uint4* wlw = wl + (size_t)(wave * 18) * 64 + lane;
  __syncthreads();

  int cur = 0;
  for (int t = 0; t < 512; ++t) {
    const unsigned short* hbc = hb[cur];
    float xA = xpb[(size_t)t * 1024 + colA];
    float xB = xpb[(size_t)t * 1024 + colB];

    // ---- G0: tiles i0..i3 (all register-resident) ----
    {
      floatx4 a0 = (floatx4)(0.f), a1 = (floatx4)(0.f);
      floatx4 a2 = (floatx4)(0.f), a3 = (floatx4)(0.f);
      FragU bf; bf.u = *(const uint4*)&hbc[hoff];
#pragma unroll
      for (int kt = 0; kt < 8; ++kt) {
        FragU bfn;
        if (kt < 7) bfn.u = *(const uint4*)&hbc[hoff + (kt + 1) * 32];
        FragU f0, f1, f2, f3;
        f0.u = wfr[0 + kt];  f1.u = wfr[8 + kt];
        f2.u = wfr[16 + kt]; f3.u = wfr[24 + kt];
        a0 = __builtin_amdgcn_mfma_f32_16x16x32_bf16(f0.s, bf.s, a0, 0, 0, 0);
        a1 = __builtin_amdgcn_mfma_f32_16x16x32_bf16(f1.s, bf.s, a1, 0, 0, 0);
        a2 = __builtin_amdgcn_mfma_f32_16x16x32_bf16(f2.s, bf.s, a2, 0, 0, 0);
        a3 = __builtin_amdgcn_mfma_f32_16x16x32_bf16(f3.s, bf.s, a3, 0, 0, 0);
        if (kt < 7) bf = bfn;
      }
      if (l15 < 2) {
        *(floatx4*)&zsh[zwoff + (2 * wave) * 16]      = a0;
        *(floatx4*)&zsh[zwoff + (2 * wave + 1) * 16]  = a1;
        *(floatx4*)&zsh[zwoff + (16 + 2 * wave) * 16] = a2;
        *(floatx4*)&zsh[zwoff + (17 + 2 * wave) * 16] = a3;
      }
    }
    // ---- G1: i4 (regs), i5 (regs kt<6 / LDS kt>=6), i6,i7 (LDS) ----
    {
      floatx4 a4 = (floatx4)(0.f), a5 = (floatx4)(0.f);
      floatx4 a6 = (floatx4)(0.f), a7 = (floatx4)(0.f);
      FragU p5a, p5b;
      p5a.u = wlw[(size_t)16 * 64];
      p5b.u = wlw[(size_t)17 * 64];
      FragU bf, p6, p7;
      bf.u = *(const uint4*)&hbc[hoff];
      p6.u = wlw[0];
      p7.u = wlw[(size_t)8 * 64];
#pragma unroll
      for (int kt = 0; kt < 8; ++kt) {
        FragU bfn, p6n, p7n;
        if (kt < 7) {
          bfn.u = *(const uint4*)&hbc[hoff + (kt + 1) * 32];
          p6n.u = wlw[(size_t)(kt + 1) * 64];
          p7n.u = wlw[(size_t)(9 + kt) * 64];
        }
        FragU f4; f4.u = wfr[32 + kt];
        a4 = __builtin_amdgcn_mfma_f32_16x16x32_bf16(f4.s, bf.s, a4, 0, 0, 0);
        if (kt < 6) {
          FragU f5; f5.u = wfr[40 + kt];
          a5 = __builtin_amdgcn_mfma_f32_16x16x32_bf16(f5.s, bf.s, a5, 0, 0, 0);
        } else if (kt == 6) {
          a5 = __builtin_amdgcn_mfma_f32_16x16x32_bf16(p5a.s, bf.s, a5, 0, 0, 0);
        } else {
          a5 = __builtin_amdgcn_mfma_f32_16x16x32_bf16(p5b.s, bf.s, a5, 0, 0, 0);
        }
        a6 = __builtin_amdgcn_mfma_f32_16x16x32_bf16(p6.s, bf.s, a6, 0, 0, 0);
        a7 = __builtin_amdgcn_mfma_f32_16x16x32_bf16(p7.s, bf.s, a7, 0, 0, 0);
        if (kt < 7) { bf = bfn; p6 = p6n; p7 = p7n; }
      }
      if (l15 < 2) {
        *(floatx4*)&zsh[zwoff + (32 + 2 * wave) * 16] = a4;
        *(floatx4*)&zsh[zwoff + (33 + 2 * wave) * 16] = a5;
        *(floatx4*)&zsh[zwoff + (48 + 2 * wave) * 16] = a6;
        *(floatx4*)&zsh[zwoff + (49 + 2 * wave) * 16] = a7;
      }
    }

    // gates: paired even/odd lanes; z from this wave's own tiles
    float zA = zsh[colA] + zsh[1024 + colA] + xA;
    float zB = zsh[colB] + zsh[1024 + colB] + xB;
    float actA = sigm(zA);                       // i (even) / f (odd)
    float tnh = tanh_(zB), sg = sigm(zB);
    float actB = e ? sg : tnh;                   // g (even) / o (odd)
    float p = actA * actB;
    float send = e ? actA : p;
    float recv = __shfl_xor(send, 1, 64);
    float cn = e ? (actA * c_ + recv)
                 : (recv * c_ + p);
    c_ = cn;
    float th = tanh_(cn);
    float hn = actB * th;                        // odd lane: o*tanh(c)
    int nxt = cur ^ 1;
    if (e) {
      enc[((size_t)b * 512 + t) * 256 + j] = hn;
      encT[((size_t)b * 256 + j) * 512 + t] = hn;
      unsigned short hh = f2bf(hn);
      hb[nxt][j] = hh;
      hb[nxt][256 + j] = f2bf(hn - bf2f(hh));
    }
    __syncthreads();
    cur = nxt;
  }
  if (e) cws[b * 256 + j] = c_;
}

// ---------------------------------------------------------------------------
// Decoder step kernel A (round-3/7 proven): cell + out + q + scores + softmax
// + ctx. One block per batch, 1024 threads.
__global__ __launch_bounds__(1024)
void k_dec_att(const float* __restrict__ enc, const float* __restrict__ encT,
               float* __restrict__ hst, float* __restrict__ cst,
               const float* __restrict__ zg, float* __restrict__ ctxg,
               const float* __restrict__ Wa, const float* __restrict__ ba,
               const float* __restrict__ W2, const float* __restrict__ b2,
               float* __restrict__ out, int p) {
  __shared__ float hsh[256], qsh[256], sc[512], smx[2];
  __shared__ float zb[1024];
  int b = blockIdx.x, tid = threadIdx.x;
  const float* encb = enc + (size_t)b * 512 * 256;

  if (p > 0) {
    if (tid < 256) {
      float zi = zg[b * 1024 + tid];
      float zf = zg[b * 1024 + 256 + tid];
      float zgg = zg[b * 1024 + 512 + tid];
      float zo = zg[b * 1024 + 768 + tid];
      float ig = sigm(zi), fg = sigm(zf), gg = tanh_(zgg), og = sigm(zo);
      float cn = fg * cst[b * 256 + tid] + ig * gg;
      cst[b * 256 + tid] = cn;
      float hn = og * tanh_(cn);
      hsh[tid] = hn;
      hst[b * 256 + tid] = hn;
    }
    __syncthreads();
    if (tid < 512) {
      int col = tid & 63, kc = tid >> 6;     // kc 0..7
      float s = 0.f;
#pragma unroll
      for (int i = 0; i < 32; ++i) {
        int k = kc * 32 + i;
        s += hsh[k] * W2[(size_t)k * 64 + col];
      }
      zb[tid] = s;
    }
    __syncthreads();
    if (tid < 64) {
      float s = b2[tid];
#pragma unroll
      for (int kc = 0; kc < 8; ++kc) s += zb[kc * 64 + tid];
      out[((size_t)b * 12 + (p - 1)) * 64 + tid] = s;
    }
  } else {
    if (tid < 256) {
      float hv = encb[(size_t)511 * 256 + tid];
      hsh[tid] = hv;
      hst[b * 256 + tid] = hv;
    }
  }
  if (p == 12) return;
  __syncthreads();

  // q = h @ Wa + ba   (k split 4 ways)
  {
    int j = tid & 255, kc = tid >> 8;
    float s = 0.f;
#pragma unroll 8
    for (int i = 0; i < 64; ++i) {
      int k = kc * 64 + i;
      s += hsh[k] * Wa[(size_t)k * 256 + j];
    }
    zb[tid] = s;
  }
  __syncthreads();
  if (tid < 256) qsh[tid] = ba[tid] + zb[tid] + zb[256 + tid] + zb[512 + tid] + zb[768 + tid];
  __syncthreads();

  // scores via encT (coalesced over hh, k split 2 ways)
  {
    int hh = tid & 511, kc = tid >> 9;
    const float* eT = encT + (size_t)b * 256 * 512;
    float s = 0.f;
#pragma unroll 8
    for (int i = 0; i < 128; ++i) {
      int k = kc * 128 + i;
      s += qsh[k] * eT[(size_t)k * 512 + hh];
    }
    zb[tid] = s;
  }
  __syncthreads();
  if (tid < 512) sc[tid] = zb[tid] + zb[512 + tid];
  __syncthreads();

  if (tid < 64) {
    float m = -3.4e38f;
#pragma unroll
    for (int r = 0; r < 8; ++r) m = fmaxf(m, sc[tid * 8 + r]);
#pragma unroll
    for (int off = 32; off >= 1; off >>= 1) m = fmaxf(m, __shfl_xor(m, off, 64));
    if (tid == 0) smx[0] = m;
  }
  __syncthreads();
  if (tid < 512) sc[tid] = __expf(sc[tid] - smx[0]);
  __syncthreads();
  if (tid < 64) {
    float s = 0.f;
#pragma unroll
    for (int r = 0; r < 8; ++r) s += sc[tid * 8 + r];
#pragma unroll
    for (int off = 32; off >= 1; off >>= 1) s += __shfl_xor(s, off, 64);
    if (tid == 0) smx[1] = 1.f / s;
  }
  __syncthreads();

  // ctx = softmax . enc   (hh split 4 ways)
  {
    int j = tid & 255, hs = tid >> 8;
    float s = 0.f;
#pragma unroll 8
    for (int r = 0; r < 128; ++r) {
      int hh = hs * 128 + r;
      s += sc[hh] * encb[(size_t)hh * 256 + j];
    }
    zb[tid] = s;
  }
  __syncthreads();
  if (tid < 256)
    ctxg[b * 256 + tid] = (zb[tid] + zb[256 + tid] + zb[512 + tid] + zb[768 + tid]) * smx[1];
}

// ---------------------------------------------------------------------------
// Decoder step kernel B (round-3/7 proven): z = ctx@Wx + h@Wh + bz, 64 blocks.
__global__ __launch_bounds__(512)
void k_dec_z(const float* __restrict__ ctxg, const float* __restrict__ hst,
             const float* __restrict__ Wx, const float* __restrict__ Wh,
             const float* __restrict__ bz, float* __restrict__ zg) {
  __shared__ float ldsx[256], ldsh[256], zsh[512];
  int chunk = blockIdx.x & 7, b = blockIdx.x >> 3;
  int tid = threadIdx.x;
  int j = tid & 127, ks = (tid >> 7) & 1, sel = tid >> 8;
  int col = chunk * 128 + j;

  if (tid < 256) ldsx[tid] = ctxg[b * 256 + tid];
  else ldsh[tid - 256] = hst[b * 256 + (tid - 256)];
  __syncthreads();

  const float* W = sel ? Wh : Wx;
  const float* v = sel ? ldsh : ldsx;
  float s = 0.f;
#pragma unroll 8
  for (int i = 0; i < 128; ++i) {
    int k = ks * 128 + i;
    s += v[k] * W[(size_t)k * 1024 + col];
  }
  zsh[tid] = s;
  __syncthreads();
  if (tid < 128)
    zg[b * 1024 + col] = bz[col] + zsh[j] + zsh[128 + j] + zsh[256 + j] + zsh[384 + j];
}

// ---------------------------------------------------------------------------
extern "C" void kernel_launch(void* const* d_in, const int* in_sizes, int n_in,
                              void* d_out, int out_size, void* d_ws, size_t ws_size,
                              hipStream_t stream) {
  const float* x  = (const float*)d_in[0];
  const float* W1 = (const float*)d_in[1];
  const float* b1 = (const float*)d_in[2];
  const float* Wx = (const float*)d_in[3];
  const float* Wh = (const float*)d_in[4];
  const float* bz = (const float*)d_in[5];
  const float* Wa = (const float*)d_in[6];
  const float* ba = (const float*)d_in[7];
  const float* W2 = (const float*)d_in[8];
  const float* b2 = (const float*)d_in[9];

  char* ws = (char*)d_ws;
  uint4* w1h  = (uint4*)(ws + OFF_W1H);
  uint4* w1l  = (uint4*)(ws + OFF_W1L);
  uint4* whsw = (uint4*)(ws + OFF_WHSW);
  float* enc  = (float*)(ws + OFF_ENC);
  float* cws  = (float*)(ws + OFF_C);
  float* xsum = (float*)(ws + OFF_XSUM);
  float* xpre = (float*)(ws + OFF_XPRE);
  float* p1   = (float*)(ws + OFF_P1);
  float* encT = (float*)(ws + OFF_ENCT);
  float* hst  = (float*)(ws + OFF_HST);
  float* ctxg = (float*)(ws + OFF_CTXG);
  float* zg   = (float*)(ws + OFF_ZG);

  k_prep_w1<<<dim3(512), dim3(1024), 0, stream>>>(W1, w1h, w1l);
  k_prep_wh<<<dim3(32), dim3(1024), 0, stream>>>(Wh, whsw);
  k_gemm1<<<dim3(256), dim3(1024), 0, stream>>>(x, w1h, w1l, p1);
  k_reduce<<<dim3(1024), dim3(1024), 0, stream>>>(p1, b1, xsum);
  k_gemm2<<<dim3(256), dim3(256), 0, stream>>>(xsum, Wx, bz, xpre);
  k_encoder<<<dim3(8), dim3(512), 0, stream>>>(whsw, xpre, enc, encT, cws);
  for (int p = 0; p <= 12; ++p) {
    k_dec_att<<<dim3(8), dim3(1024), 0, stream>>>(enc, encT, hst, cws, zg, ctxg,
                                                  Wa, ba, W2, b2, (float*)d_out, p);
    if (p < 12)
      k_dec_z<<<dim3(64), dim3(512), 0, stream>>>(ctxg, hst, Wx, Wh, bz, zg);
  }
}